// Round 6
// baseline (353.440 us; speedup 1.0000x reference)
//
#include <hip/hip_runtime.h>
#include <math.h>

#define B_ 2
#define N_ 6
#define D_ 59
#define FH 32
#define FW 88
#define C_ 80
#define NX 360
#define NY 360
#define P_PER_B (N_*D_*FH*FW)     // 996,864
#define NPTS (B_*P_PER_B)         // 1,993,728 = 7788*256
#define NCELL (NX*NY)             // 129,600
#define NC (B_*NCELL)             // 259,200 cells
#define NCP (254*1024)            // 260,096 padded (= 254*256 int4)
#define OUT4 (B_*C_*NCELL/4)      // 5,184,000 float4 in out
#define SUB 8                     // points per gather slot

// Static device scratch; every read location rewritten each launch (replay safe).
__device__ float g_inv[B_*N_*16];
__device__ int   g_code[NPTS];     // cell id or -1
__device__ __align__(16) int g_cnt[NCP];
__device__ int   g_escan[NCP];
__device__ int   g_bsum[254];
__device__ int   g_bpre[254];
__device__ int   g_offs[NC+1];     // global exclusive offsets (+ total at [NC])
__device__ int   g_cur[NC];        // fill cursors
__device__ __align__(16) int g_plist[NPTS]; // cell-sorted point ids
__device__ __align__(16) int g_clist[NPTS]; // cell id per sorted position

// ---- 1) init: zero d_out (83MB) + zero counts + invert the 12 matrices
__global__ void k_init(const float* __restrict__ l2i, float* __restrict__ out) {
  int i = blockIdx.x*256 + threadIdx.x;            // grid exact: OUT4/256 blocks
  ((float4*)out)[i] = make_float4(0.f,0.f,0.f,0.f);
  if (blockIdx.x < 254) {
    ((int4*)g_cnt)[i] = make_int4(0,0,0,0);
  }
  if (blockIdx.x == 20249 && threadIdx.x < B_*N_) {
    int m = threadIdx.x;
    double a[4][4], inv[4][4];
    for (int r=0;r<4;r++) for (int j=0;j<4;j++){
      a[r][j] = (double)l2i[m*16+r*4+j];
      inv[r][j] = (r==j)?1.0:0.0;
    }
    for (int k=0;k<4;k++){
      int p=k; double mx=fabs(a[k][k]);
      for (int r=k+1;r<4;r++){ double v=fabs(a[r][k]); if (v>mx){mx=v;p=r;} }
      if (p!=k){
        for (int j=0;j<4;j++){
          double t=a[k][j]; a[k][j]=a[p][j]; a[p][j]=t;
          t=inv[k][j]; inv[k][j]=inv[p][j]; inv[p][j]=t;
        }
      }
      double pi = 1.0/a[k][k];
      for (int j=0;j<4;j++){ a[k][j]*=pi; inv[k][j]*=pi; }
      for (int r=0;r<4;r++) if (r!=k){
        double f=a[r][k];
        for (int j=0;j<4;j++){ a[r][j]-=f*a[k][j]; inv[r][j]-=f*inv[k][j]; }
      }
    }
    for (int r=0;r<4;r++) for (int j=0;j<4;j++)
      g_inv[m*16+r*4+j] = (float)inv[r][j];
  }
}

// ---- 2) geometry -> cell code + wave-collapsed per-cell counts
__global__ void k_geom(const float* __restrict__ itrans, const float* __restrict__ iscale) {
#pragma clang fp contract(off)
  int p = blockIdx.x*256 + threadIdx.x;            // grid exact: NPTS/256
  int b  = p / P_PER_B;
  int r  = p - b*P_PER_B;
  int n  = r / (D_*FH*FW);
  int r2 = r - n*(D_*FH*FW);
  int d  = r2 / (FH*FW);
  int r3 = r2 - d*(FH*FW);
  int h  = r3 / FW;
  int w  = r3 - h*FW;
  int bn = b*N_ + n;

  float xw = (float)((double)w * (703.0/87.0));    // np.linspace in f64, rounded
  float yh = (float)((double)h * (255.0/31.0));
  float dd = (float)(d + 1);                       // ds = 1..59

  float t0 = itrans[bn*3+0], t1 = itrans[bn*3+1], t2 = itrans[bn*3+2];
  float s  = iscale[bn];

  float px = xw + t0, py = yh + t1, pd = dd + t2;
  float x0 = px / s, x1 = py / s;
  float p0 = x0*pd, p1 = x1*pd, p2 = pd;

  const float* iv = &g_inv[bn*16];
  float gx = ((iv[0]*p0 + iv[1]*p1) + iv[2]*p2)  + iv[3]*1.0f;
  float gy = ((iv[4]*p0 + iv[5]*p1) + iv[6]*p2)  + iv[7]*1.0f;
  float gz = ((iv[8]*p0 + iv[9]*p1) + iv[10]*p2) + iv[11]*1.0f;

  int vx = (int)((gx + 54.0f) / 0.3f);             // trunc == astype(int32)
  int vy = (int)((gy + 54.0f) / 0.3f);
  int vz = (int)((gz + 10.0f) / 20.0f);

  bool ok = (vx>=0) & (vx<NX) & (vy>=0) & (vy<NY) & (vz>=0) & (vz<1);
  int code = ok ? (b*NCELL + vx*NY + vy) : -1;
  g_code[p] = code;

  int lane = threadIdx.x & 63;
  int prev = __shfl_up(code, 1);
  bool leader = (lane == 0) || (code != prev);
  unsigned long long m = __ballot(leader);
  if (leader && code >= 0) {
    unsigned long long above = (lane < 63) ? (m >> (lane+1)) : 0ULL;
    int len = above ? __ffsll(above) : (64 - lane);
    atomicAdd(&g_cnt[code], len);
  }
}

// ---- 3a) per-block exclusive scan (1024) over counts
__global__ void k_scanA() {
  __shared__ int sd[1024];
  int t = threadIdx.x;
  int i = blockIdx.x*1024 + t;
  int v = g_cnt[i];
  sd[t] = v;
  for (int off=1; off<1024; off<<=1) {
    __syncthreads();
    int x = (t >= off) ? sd[t-off] : 0;
    __syncthreads();
    sd[t] += x;
  }
  g_escan[i] = sd[t] - v;
  if (t == 1023) g_bsum[blockIdx.x] = sd[1023];
}

// ---- 3b) scan the 254 block sums
__global__ void k_scanB() {
  __shared__ int sd[256];
  int t = threadIdx.x;
  int v = (t < 254) ? g_bsum[t] : 0;
  sd[t] = v;
  for (int off=1; off<256; off<<=1) {
    __syncthreads();
    int x = (t >= off) ? sd[t-off] : 0;
    __syncthreads();
    sd[t] += x;
  }
  if (t < 254) g_bpre[t] = sd[t] - v;
  if (t == 255) g_offs[NC] = sd[255];              // total valid count
}

// ---- 3c) add back -> global offsets + cursors
__global__ void k_scanC() {
  int i = blockIdx.x*1024 + threadIdx.x;
  if (i < NC) {
    int o = g_escan[i] + g_bpre[blockIdx.x];
    g_offs[i] = o;
    g_cur[i]  = o;
  }
}

// ---- 4) fill cell-sorted lists, wave-collapsed cursor bumps
__global__ void k_fill() {
  int p = blockIdx.x*256 + threadIdx.x;            // grid exact
  int code = g_code[p];
  int lane = threadIdx.x & 63;
  int prev = __shfl_up(code, 1);
  bool leader = (lane == 0) || (code != prev);
  unsigned long long m = __ballot(leader);
  unsigned long long mask_le = (lane==63) ? ~0ULL : ((1ULL << (lane+1)) - 1ULL);
  int leaderLane = 63 - __clzll(m & mask_le);
  int pos0 = 0;
  if (leader && code >= 0) {
    unsigned long long above = (lane < 63) ? (m >> (lane+1)) : 0ULL;
    int len = above ? __ffsll(above) : (64 - lane);
    pos0 = atomicAdd(&g_cur[code], len);
  }
  pos0 = __shfl(pos0, leaderLane);
  if (code >= 0) {
    int pos = pos0 + (lane - leaderLane);
    g_plist[pos] = p;
    g_clist[pos] = code;
  }
}

// ---- 5) gather v3: slot = 8 sorted points, thread = (slot, c4).
// All loads prefetched into statically-indexed registers (8-deep MLP),
// then pure-VALU run-collapse; exclusive cells -> plain stores.
__device__ __forceinline__ void flush_run(float* __restrict__ out, int c, int c4,
                                          int s0, int s1,
                                          float ax, float ay, float az, float aw) {
  int o0 = g_offs[c], o1 = g_offs[c+1];
  int b = c / NCELL;
  int xy = c - b*NCELL;
  float* dst = out + (size_t)(b*C_ + c4*4)*NCELL + xy;
  if (o0 >= s0 && o1 <= s1) {                      // exclusive owner
    dst[0]       = ax;
    dst[NCELL]   = ay;
    dst[2*NCELL] = az;
    dst[3*NCELL] = aw;
  } else {
    atomicAdd(dst,         ax);
    atomicAdd(dst+NCELL,   ay);
    atomicAdd(dst+2*NCELL, az);
    atomicAdd(dst+3*NCELL, aw);
  }
}

__global__ void __launch_bounds__(320) k_gather(const float* __restrict__ feats,
                                                float* __restrict__ out) {
  int T = g_offs[NC];
  int nslots = (T + SUB - 1) / SUB;
  int c4 = threadIdx.x % 20;
  int slotInBlk = threadIdx.x / 20;                // 0..15
  const float4* f4 = (const float4*)feats;

  for (int ss = blockIdx.x*16 + slotInBlk; ss < nslots; ss += gridDim.x*16) {
    int s0 = ss*SUB;
    if (T - s0 >= SUB) {
      int4 ca = ((const int4*)(g_clist + s0))[0];
      int4 cb = ((const int4*)(g_clist + s0))[1];
      int4 pa = ((const int4*)(g_plist + s0))[0];
      int4 pb = ((const int4*)(g_plist + s0))[1];
      int c[SUB]  = {ca.x,ca.y,ca.z,ca.w, cb.x,cb.y,cb.z,cb.w};
      int pl[SUB] = {pa.x,pa.y,pa.z,pa.w, pb.x,pb.y,pb.z,pb.w};
      float4 v[SUB];
      #pragma unroll
      for (int k=0;k<SUB;++k) v[k] = f4[(size_t)pl[k]*20 + c4];
      int cur = c[0];
      float ax=v[0].x, ay=v[0].y, az=v[0].z, aw=v[0].w;
      #pragma unroll
      for (int k=1;k<SUB;++k) {
        if (c[k] != cur) {
          flush_run(out, cur, c4, s0, s0+SUB, ax, ay, az, aw);
          cur = c[k]; ax=v[k].x; ay=v[k].y; az=v[k].z; aw=v[k].w;
        } else {
          ax+=v[k].x; ay+=v[k].y; az+=v[k].z; aw+=v[k].w;
        }
      }
      flush_run(out, cur, c4, s0, s0+SUB, ax, ay, az, aw);
    } else {
      // tail slot (rare): guarded serial loop
      int cur = g_clist[s0];
      float ax=0.f, ay=0.f, az=0.f, aw=0.f;
      for (int j = s0; j < T; ++j) {
        int cc = g_clist[j];
        if (cc != cur) {
          flush_run(out, cur, c4, s0, T, ax, ay, az, aw);
          cur = cc; ax=ay=az=aw=0.f;
        }
        float4 vv = f4[(size_t)g_plist[j]*20 + c4];
        ax+=vv.x; ay+=vv.y; az+=vv.z; aw+=vv.w;
      }
      flush_run(out, cur, c4, s0, T, ax, ay, az, aw);
    }
  }
}

extern "C" void kernel_launch(void* const* d_in, const int* in_sizes, int n_in,
                              void* d_out, int out_size, void* d_ws, size_t ws_size,
                              hipStream_t stream) {
  const float* feats  = (const float*)d_in[0];
  const float* itrans = (const float*)d_in[1];
  const float* iscale = (const float*)d_in[2];
  const float* l2i    = (const float*)d_in[3];
  float* out = (float*)d_out;

  k_init<<<OUT4/256, 256, 0, stream>>>(l2i, out);         // 20,250 blocks
  k_geom<<<NPTS/256, 256, 0, stream>>>(itrans, iscale);   // 7,788 blocks
  k_scanA<<<254, 1024, 0, stream>>>();
  k_scanB<<<1, 256, 0, stream>>>();
  k_scanC<<<254, 1024, 0, stream>>>();
  k_fill<<<NPTS/256, 256, 0, stream>>>();                 // 7,788 blocks
  k_gather<<<1360, 320, 0, stream>>>(feats, out);         // 1,360 blocks
}

// Round 7
// 306.401 us; speedup vs baseline: 1.1535x; 1.1535x over previous
//
#include <hip/hip_runtime.h>
#include <math.h>

#define B_ 2
#define N_ 6
#define D_ 59
#define FH 32
#define FW 88
#define C_ 80
#define NX 360
#define NY 360
#define P_PER_B (N_*D_*FH*FW)     // 996,864
#define NPTS (B_*P_PER_B)         // 1,993,728 = 7788*256
#define NCELL (NX*NY)             // 129,600
#define NC (B_*NCELL)             // 259,200 cells
#define NCP (254*1024)            // 260,096 padded (= 254*256 int4)
#define OUT4 (B_*C_*NCELL/4)      // 5,184,000 float4 in out
#define SUB 8                     // points per gather slot
#define MAXSLOTS (NPTS/SUB)       // 249,216

// Static device scratch; every read location rewritten each launch (replay safe).
__device__ float g_inv[B_*N_*16];
__device__ int   g_code[NPTS];     // cell id or -1
__device__ __align__(16) int g_cnt[NCP];
__device__ int   g_escan[NCP];
__device__ int   g_bsum[254];
__device__ int   g_bpre[254];
__device__ int   g_offs[NC+1];     // global exclusive offsets (+ total at [NC])
__device__ int   g_cur[NC];        // fill cursors
__device__ __align__(16) int g_plist[NPTS]; // cell-sorted point ids
__device__ __align__(16) int g_clist[NPTS]; // cell id per sorted position
// no-atomic boundary machinery:
__device__ int   g_lastCell[MAXSLOTS];               // owner-run cell per slot, or -1
__device__ __align__(16) float g_first4[MAXSLOTS*C_]; // left-crossing run partial
__device__ __align__(16) float g_last4[MAXSLOTS*C_];  // right-crossing (owner) partial

// ---- 1) init: zero d_out (83MB) + zero counts + invert the 12 matrices
__global__ void k_init(const float* __restrict__ l2i, float* __restrict__ out) {
  int i = blockIdx.x*256 + threadIdx.x;            // grid exact: OUT4/256 blocks
  ((float4*)out)[i] = make_float4(0.f,0.f,0.f,0.f);
  if (blockIdx.x < 254) {
    ((int4*)g_cnt)[i] = make_int4(0,0,0,0);
  }
  if (blockIdx.x == 20249 && threadIdx.x < B_*N_) {
    int m = threadIdx.x;
    double a[4][4], inv[4][4];
    for (int r=0;r<4;r++) for (int j=0;j<4;j++){
      a[r][j] = (double)l2i[m*16+r*4+j];
      inv[r][j] = (r==j)?1.0:0.0;
    }
    for (int k=0;k<4;k++){
      int p=k; double mx=fabs(a[k][k]);
      for (int r=k+1;r<4;r++){ double v=fabs(a[r][k]); if (v>mx){mx=v;p=r;} }
      if (p!=k){
        for (int j=0;j<4;j++){
          double t=a[k][j]; a[k][j]=a[p][j]; a[p][j]=t;
          t=inv[k][j]; inv[k][j]=inv[p][j]; inv[p][j]=t;
        }
      }
      double pi = 1.0/a[k][k];
      for (int j=0;j<4;j++){ a[k][j]*=pi; inv[k][j]*=pi; }
      for (int r=0;r<4;r++) if (r!=k){
        double f=a[r][k];
        for (int j=0;j<4;j++){ a[r][j]-=f*a[k][j]; inv[r][j]-=f*inv[k][j]; }
      }
    }
    for (int r=0;r<4;r++) for (int j=0;j<4;j++)
      g_inv[m*16+r*4+j] = (float)inv[r][j];
  }
}

// ---- 2) geometry -> cell code + wave-collapsed per-cell counts
__global__ void k_geom(const float* __restrict__ itrans, const float* __restrict__ iscale) {
#pragma clang fp contract(off)
  int p = blockIdx.x*256 + threadIdx.x;            // grid exact: NPTS/256
  int b  = p / P_PER_B;
  int r  = p - b*P_PER_B;
  int n  = r / (D_*FH*FW);
  int r2 = r - n*(D_*FH*FW);
  int d  = r2 / (FH*FW);
  int r3 = r2 - d*(FH*FW);
  int h  = r3 / FW;
  int w  = r3 - h*FW;
  int bn = b*N_ + n;

  float xw = (float)((double)w * (703.0/87.0));    // np.linspace in f64, rounded
  float yh = (float)((double)h * (255.0/31.0));
  float dd = (float)(d + 1);                       // ds = 1..59

  float t0 = itrans[bn*3+0], t1 = itrans[bn*3+1], t2 = itrans[bn*3+2];
  float s  = iscale[bn];

  float px = xw + t0, py = yh + t1, pd = dd + t2;
  float x0 = px / s, x1 = py / s;
  float p0 = x0*pd, p1 = x1*pd, p2 = pd;

  const float* iv = &g_inv[bn*16];
  float gx = ((iv[0]*p0 + iv[1]*p1) + iv[2]*p2)  + iv[3]*1.0f;
  float gy = ((iv[4]*p0 + iv[5]*p1) + iv[6]*p2)  + iv[7]*1.0f;
  float gz = ((iv[8]*p0 + iv[9]*p1) + iv[10]*p2) + iv[11]*1.0f;

  int vx = (int)((gx + 54.0f) / 0.3f);             // trunc == astype(int32)
  int vy = (int)((gy + 54.0f) / 0.3f);
  int vz = (int)((gz + 10.0f) / 20.0f);

  bool ok = (vx>=0) & (vx<NX) & (vy>=0) & (vy<NY) & (vz>=0) & (vz<1);
  int code = ok ? (b*NCELL + vx*NY + vy) : -1;
  g_code[p] = code;

  int lane = threadIdx.x & 63;
  int prev = __shfl_up(code, 1);
  bool leader = (lane == 0) || (code != prev);
  unsigned long long m = __ballot(leader);
  if (leader && code >= 0) {
    unsigned long long above = (lane < 63) ? (m >> (lane+1)) : 0ULL;
    int len = above ? __ffsll(above) : (64 - lane);
    atomicAdd(&g_cnt[code], len);
  }
}

// ---- 3a) per-block exclusive scan (1024) over counts
__global__ void k_scanA() {
  __shared__ int sd[1024];
  int t = threadIdx.x;
  int i = blockIdx.x*1024 + t;
  int v = g_cnt[i];
  sd[t] = v;
  for (int off=1; off<1024; off<<=1) {
    __syncthreads();
    int x = (t >= off) ? sd[t-off] : 0;
    __syncthreads();
    sd[t] += x;
  }
  g_escan[i] = sd[t] - v;
  if (t == 1023) g_bsum[blockIdx.x] = sd[1023];
}

// ---- 3b) scan the 254 block sums
__global__ void k_scanB() {
  __shared__ int sd[256];
  int t = threadIdx.x;
  int v = (t < 254) ? g_bsum[t] : 0;
  sd[t] = v;
  for (int off=1; off<256; off<<=1) {
    __syncthreads();
    int x = (t >= off) ? sd[t-off] : 0;
    __syncthreads();
    sd[t] += x;
  }
  if (t < 254) g_bpre[t] = sd[t] - v;
  if (t == 255) g_offs[NC] = sd[255];              // total valid count
}

// ---- 3c) add back -> global offsets + cursors
__global__ void k_scanC() {
  int i = blockIdx.x*1024 + threadIdx.x;
  if (i < NC) {
    int o = g_escan[i] + g_bpre[blockIdx.x];
    g_offs[i] = o;
    g_cur[i]  = o;
  }
}

// ---- 4) fill cell-sorted lists, wave-collapsed cursor bumps
__global__ void k_fill() {
  int p = blockIdx.x*256 + threadIdx.x;            // grid exact
  int code = g_code[p];
  int lane = threadIdx.x & 63;
  int prev = __shfl_up(code, 1);
  bool leader = (lane == 0) || (code != prev);
  unsigned long long m = __ballot(leader);
  unsigned long long mask_le = (lane==63) ? ~0ULL : ((1ULL << (lane+1)) - 1ULL);
  int leaderLane = 63 - __clzll(m & mask_le);
  int pos0 = 0;
  if (leader && code >= 0) {
    unsigned long long above = (lane < 63) ? (m >> (lane+1)) : 0ULL;
    int len = above ? __ffsll(above) : (64 - lane);
    pos0 = atomicAdd(&g_cur[code], len);
  }
  pos0 = __shfl(pos0, leaderLane);
  if (code >= 0) {
    int pos = pos0 + (lane - leaderLane);
    g_plist[pos] = p;
    g_clist[pos] = code;
  }
}

// ---- 5) gather: slot = 8 sorted points, thread = (slot, c4). Full register
// prefetch (8-deep MLP). ZERO global atomics: runs fully inside the slot ->
// direct store; left-crossing run -> partial to g_first4[slot]; run starting
// here and crossing right -> partial to g_last4[slot] + owner mark. k_fixup
// stitches the split runs (consecutive slots, since runs are contiguous).
__global__ void __launch_bounds__(320) k_gather(const float* __restrict__ feats,
                                                float* __restrict__ out) {
  int T = g_offs[NC];
  int nslots = (T + SUB - 1) / SUB;
  int c4 = threadIdx.x % 20;
  int slotInBlk = threadIdx.x / 20;                // 0..15
  const float4* f4 = (const float4*)feats;

  for (int ss = blockIdx.x*16 + slotInBlk; ss < nslots; ss += gridDim.x*16) {
    int s0 = ss*SUB;
    int s1 = min(s0 + SUB, T);
    int lastc = -1;

    auto FLUSH = [&](int c, float ax, float ay, float az, float aw) {
      int o0 = g_offs[c], o1 = g_offs[c+1];
      bool crossL = o0 < s0, crossR = o1 > s1;
      if (!crossL && !crossR) {                    // exclusive -> direct store
        int b = c / NCELL;
        int xy = c - b*NCELL;
        float* dst = out + (size_t)(b*C_ + c4*4)*NCELL + xy;
        dst[0]       = ax;
        dst[NCELL]   = ay;
        dst[2*NCELL] = az;
        dst[3*NCELL] = aw;
      } else if (crossL) {                         // consumed by earlier owner
        ((float4*)g_first4)[ss*20 + c4] = make_float4(ax, ay, az, aw);
      } else {                                     // starts here, crosses right
        ((float4*)g_last4)[ss*20 + c4] = make_float4(ax, ay, az, aw);
        lastc = c;
      }
    };

    if (s1 - s0 == SUB) {
      int4 ca = ((const int4*)(g_clist + s0))[0];
      int4 cb = ((const int4*)(g_clist + s0))[1];
      int4 pa = ((const int4*)(g_plist + s0))[0];
      int4 pb = ((const int4*)(g_plist + s0))[1];
      int c[SUB]  = {ca.x,ca.y,ca.z,ca.w, cb.x,cb.y,cb.z,cb.w};
      int pl[SUB] = {pa.x,pa.y,pa.z,pa.w, pb.x,pb.y,pb.z,pb.w};
      float4 v[SUB];
      #pragma unroll
      for (int k=0;k<SUB;++k) v[k] = f4[(size_t)pl[k]*20 + c4];
      int cur = c[0];
      float ax=v[0].x, ay=v[0].y, az=v[0].z, aw=v[0].w;
      #pragma unroll
      for (int k=1;k<SUB;++k) {
        if (c[k] != cur) {
          FLUSH(cur, ax, ay, az, aw);
          cur = c[k]; ax=v[k].x; ay=v[k].y; az=v[k].z; aw=v[k].w;
        } else {
          ax+=v[k].x; ay+=v[k].y; az+=v[k].z; aw+=v[k].w;
        }
      }
      FLUSH(cur, ax, ay, az, aw);
    } else {
      // tail slot (rare): guarded serial loop; crossR impossible (s1 == T)
      int cur = g_clist[s0];
      float ax=0.f, ay=0.f, az=0.f, aw=0.f;
      for (int j = s0; j < s1; ++j) {
        int cc = g_clist[j];
        if (cc != cur) {
          FLUSH(cur, ax, ay, az, aw);
          cur = cc; ax=ay=az=aw=0.f;
        }
        float4 vv = f4[(size_t)g_plist[j]*20 + c4];
        ax+=vv.x; ay+=vv.y; az+=vv.z; aw+=vv.w;
      }
      FLUSH(cur, ax, ay, az, aw);
    }
    if (c4 == 0) g_lastCell[ss] = lastc;
  }
}

// ---- 6) fixup: owner slot s (lastCell[s]=c) sums last4[s] + first4[s+1..sE]
// and plain-stores the stitched run. Exclusive ownership -> no atomics.
__global__ void __launch_bounds__(320) k_fixup(float* __restrict__ out) {
  int T = g_offs[NC];
  int nslots = (T + SUB - 1) / SUB;
  int c4 = threadIdx.x % 20;
  int slotInBlk = threadIdx.x / 20;
  for (int s = blockIdx.x*16 + slotInBlk; s < nslots; s += gridDim.x*16) {
    int c = g_lastCell[s];
    if (c < 0) continue;
    int o1 = g_offs[c+1];
    int sE = (o1 - 1) / SUB;                       // slot holding run's last point
    float4 tot = ((const float4*)g_last4)[s*20 + c4];
    for (int t = s+1; t <= sE; ++t) {
      float4 u = ((const float4*)g_first4)[t*20 + c4];
      tot.x+=u.x; tot.y+=u.y; tot.z+=u.z; tot.w+=u.w;
    }
    int b = c / NCELL;
    int xy = c - b*NCELL;
    float* dst = out + (size_t)(b*C_ + c4*4)*NCELL + xy;
    dst[0]       = tot.x;
    dst[NCELL]   = tot.y;
    dst[2*NCELL] = tot.z;
    dst[3*NCELL] = tot.w;
  }
}

extern "C" void kernel_launch(void* const* d_in, const int* in_sizes, int n_in,
                              void* d_out, int out_size, void* d_ws, size_t ws_size,
                              hipStream_t stream) {
  const float* feats  = (const float*)d_in[0];
  const float* itrans = (const float*)d_in[1];
  const float* iscale = (const float*)d_in[2];
  const float* l2i    = (const float*)d_in[3];
  float* out = (float*)d_out;

  k_init<<<OUT4/256, 256, 0, stream>>>(l2i, out);         // 20,250 blocks
  k_geom<<<NPTS/256, 256, 0, stream>>>(itrans, iscale);   // 7,788 blocks
  k_scanA<<<254, 1024, 0, stream>>>();
  k_scanB<<<1, 256, 0, stream>>>();
  k_scanC<<<254, 1024, 0, stream>>>();
  k_fill<<<NPTS/256, 256, 0, stream>>>();                 // 7,788 blocks
  k_gather<<<2048, 320, 0, stream>>>(feats, out);         // grid-stride
  k_fixup<<<512, 320, 0, stream>>>(out);                  // grid-stride
}

// Round 8
// 139.671 us; speedup vs baseline: 2.5305x; 2.1937x over previous
//
#include <hip/hip_runtime.h>
#include <math.h>

#define B_ 2
#define N_ 6
#define D_ 59
#define FH 32
#define FW 88
#define C_ 80
#define NX 360
#define NY 360
#define P_PER_B (N_*D_*FH*FW)     // 996,864
#define NPTS (B_*P_PER_B)         // 1,993,728 = 7788*256
#define NCELL (NX*NY)             // 129,600
#define NC (B_*NCELL)             // 259,200 cells
#define NCP (254*1024)            // 260,096 padded (= 254*256 int4)
#define OUT4 (B_*C_*NCELL/4)      // 5,184,000 float4 in out
#define SMAX 48                   // cells <= SMAX points -> thread-mode
#define CHK 192                   // points per wave-chunk (divisible by 3)
#define MAXCHK (NC + NPTS/CHK)    // bound on chunk count
#define BBLK 512                  // wave-mode blocks (low ids, start first)
#define TOTBLK 2048
#define SBLK (TOTBLK - BBLK)

// Static device scratch; every read location rewritten each launch (replay safe).
__device__ float g_inv[B_*N_*16];
__device__ int   g_code[NPTS];     // cell id or -1
__device__ __align__(16) int g_cnt[NCP];
__device__ int   g_escan[NCP];
__device__ int   g_bsum[254];
__device__ int   g_bpre[254];
__device__ int   g_offs[NC+1];     // global exclusive offsets (+ total at [NC])
__device__ int   g_cur[NC];        // fill cursors
__device__ __align__(16) int g_plist[NPTS]; // cell-sorted point ids
__device__ int   g_nS;             // small-cell count
__device__ int   g_nB;             // wave-chunk count
__device__ int2  g_cellS[NC];      // {cell, o0}
__device__ int2  g_chunkB[MAXCHK]; // {cell, chunk start}

// ---- 1) init: zero d_out (83MB) + zero counts/counters + invert the 12 matrices
__global__ void k_init(const float* __restrict__ l2i, float* __restrict__ out) {
  int i = blockIdx.x*256 + threadIdx.x;            // grid exact: OUT4/256 blocks
  ((float4*)out)[i] = make_float4(0.f,0.f,0.f,0.f);
  if (blockIdx.x < 254) {
    ((int4*)g_cnt)[i] = make_int4(0,0,0,0);
  }
  if (blockIdx.x == 0 && threadIdx.x == 0) { g_nS = 0; g_nB = 0; }
  if (blockIdx.x == 20249 && threadIdx.x < B_*N_) {
    int m = threadIdx.x;
    double a[4][4], inv[4][4];
    for (int r=0;r<4;r++) for (int j=0;j<4;j++){
      a[r][j] = (double)l2i[m*16+r*4+j];
      inv[r][j] = (r==j)?1.0:0.0;
    }
    for (int k=0;k<4;k++){
      int p=k; double mx=fabs(a[k][k]);
      for (int r=k+1;r<4;r++){ double v=fabs(a[r][k]); if (v>mx){mx=v;p=r;} }
      if (p!=k){
        for (int j=0;j<4;j++){
          double t=a[k][j]; a[k][j]=a[p][j]; a[p][j]=t;
          t=inv[k][j]; inv[k][j]=inv[p][j]; inv[p][j]=t;
        }
      }
      double pi = 1.0/a[k][k];
      for (int j=0;j<4;j++){ a[k][j]*=pi; inv[k][j]*=pi; }
      for (int r=0;r<4;r++) if (r!=k){
        double f=a[r][k];
        for (int j=0;j<4;j++){ a[r][j]-=f*a[k][j]; inv[r][j]-=f*inv[k][j]; }
      }
    }
    for (int r=0;r<4;r++) for (int j=0;j<4;j++)
      g_inv[m*16+r*4+j] = (float)inv[r][j];
  }
}

// ---- 2) geometry -> cell code + wave-collapsed per-cell counts
__global__ void k_geom(const float* __restrict__ itrans, const float* __restrict__ iscale) {
#pragma clang fp contract(off)
  int p = blockIdx.x*256 + threadIdx.x;            // grid exact: NPTS/256
  int b  = p / P_PER_B;
  int r  = p - b*P_PER_B;
  int n  = r / (D_*FH*FW);
  int r2 = r - n*(D_*FH*FW);
  int d  = r2 / (FH*FW);
  int r3 = r2 - d*(FH*FW);
  int h  = r3 / FW;
  int w  = r3 - h*FW;
  int bn = b*N_ + n;

  float xw = (float)((double)w * (703.0/87.0));    // np.linspace in f64, rounded
  float yh = (float)((double)h * (255.0/31.0));
  float dd = (float)(d + 1);                       // ds = 1..59

  float t0 = itrans[bn*3+0], t1 = itrans[bn*3+1], t2 = itrans[bn*3+2];
  float s  = iscale[bn];

  float px = xw + t0, py = yh + t1, pd = dd + t2;
  float x0 = px / s, x1 = py / s;
  float p0 = x0*pd, p1 = x1*pd, p2 = pd;

  const float* iv = &g_inv[bn*16];
  float gx = ((iv[0]*p0 + iv[1]*p1) + iv[2]*p2)  + iv[3]*1.0f;
  float gy = ((iv[4]*p0 + iv[5]*p1) + iv[6]*p2)  + iv[7]*1.0f;
  float gz = ((iv[8]*p0 + iv[9]*p1) + iv[10]*p2) + iv[11]*1.0f;

  int vx = (int)((gx + 54.0f) / 0.3f);             // trunc == astype(int32)
  int vy = (int)((gy + 54.0f) / 0.3f);
  int vz = (int)((gz + 10.0f) / 20.0f);

  bool ok = (vx>=0) & (vx<NX) & (vy>=0) & (vy<NY) & (vz>=0) & (vz<1);
  int code = ok ? (b*NCELL + vx*NY + vy) : -1;
  g_code[p] = code;

  int lane = threadIdx.x & 63;
  int prev = __shfl_up(code, 1);
  bool leader = (lane == 0) || (code != prev);
  unsigned long long m = __ballot(leader);
  if (leader && code >= 0) {
    unsigned long long above = (lane < 63) ? (m >> (lane+1)) : 0ULL;
    int len = above ? __ffsll(above) : (64 - lane);
    atomicAdd(&g_cnt[code], len);
  }
}

// ---- 3a) per-block exclusive scan (1024) over counts
__global__ void k_scanA() {
  __shared__ int sd[1024];
  int t = threadIdx.x;
  int i = blockIdx.x*1024 + t;
  int v = g_cnt[i];
  sd[t] = v;
  for (int off=1; off<1024; off<<=1) {
    __syncthreads();
    int x = (t >= off) ? sd[t-off] : 0;
    __syncthreads();
    sd[t] += x;
  }
  g_escan[i] = sd[t] - v;
  if (t == 1023) g_bsum[blockIdx.x] = sd[1023];
}

// ---- 3b) scan the 254 block sums
__global__ void k_scanB() {
  __shared__ int sd[256];
  int t = threadIdx.x;
  int v = (t < 254) ? g_bsum[t] : 0;
  sd[t] = v;
  for (int off=1; off<256; off<<=1) {
    __syncthreads();
    int x = (t >= off) ? sd[t-off] : 0;
    __syncthreads();
    sd[t] += x;
  }
  if (t < 254) g_bpre[t] = sd[t] - v;
  if (t == 255) g_offs[NC] = sd[255];              // total valid count
}

// ---- 3c) add back -> offsets + cursors, FUSED with cell classification:
// len<=SMAX -> S list (wave-aggregated append); len>SMAX -> chunk list.
__global__ void k_scanC() {
  int i = blockIdx.x*1024 + threadIdx.x;
  bool inb = (i < NC);
  int o = 0, len = 0;
  if (inb) {
    o = g_escan[i] + g_bpre[blockIdx.x];
    g_offs[i] = o;
    g_cur[i]  = o;
    len = g_cnt[i];
  }
  int lane = threadIdx.x & 63;
  bool isS = inb && (len > 0) && (len <= SMAX);
  unsigned long long m = __ballot(isS);
  if (m) {
    int ldr = __ffsll((long long)m) - 1;
    int base = 0;
    if (lane == ldr) base = atomicAdd(&g_nS, (int)__popcll(m));
    base = __shfl(base, ldr);
    if (isS) {
      int rank = __popcll(m & ((1ULL << lane) - 1ULL));
      g_cellS[base + rank] = make_int2(i, o);
    }
  }
  if (inb && len > SMAX) {
    int nch = (len + CHK - 1) / CHK;
    int base = atomicAdd(&g_nB, nch);
    for (int k = 0; k < nch; ++k)
      g_chunkB[base + k] = make_int2(i, o + k*CHK);
  }
}

// ---- 4) fill cell-sorted point list, wave-collapsed cursor bumps
__global__ void k_fill() {
  int p = blockIdx.x*256 + threadIdx.x;            // grid exact
  int code = g_code[p];
  int lane = threadIdx.x & 63;
  int prev = __shfl_up(code, 1);
  bool leader = (lane == 0) || (code != prev);
  unsigned long long m = __ballot(leader);
  unsigned long long mask_le = (lane==63) ? ~0ULL : ((1ULL << (lane+1)) - 1ULL);
  int leaderLane = 63 - __clzll(m & mask_le);
  int pos0 = 0;
  if (leader && code >= 0) {
    unsigned long long above = (lane < 63) ? (m >> (lane+1)) : 0ULL;
    int len = above ? __ffsll(above) : (64 - lane);
    pos0 = atomicAdd(&g_cur[code], len);
  }
  pos0 = __shfl(pos0, leaderLane);
  if (code >= 0) {
    int pos = pos0 + (lane - leaderLane);
    g_plist[pos] = p;
  }
}

// ---- 5) gather: one worker per cell (no boundaries, no fixup).
// Blocks [0,BBLK): wave-mode — one 64-lane wave per <=CHK-point chunk
//   (3 points x 20 channel-groups, 4-deep batches, shfl-reduce).
// Blocks [BBLK,TOTBLK): thread-mode — thread per (small cell, c4),
//   8-deep batched prefetch, single exclusive float4-group store.
__global__ void __launch_bounds__(256) k_gather(const float* __restrict__ feats,
                                                float* __restrict__ out) {
  const float4* f4 = (const float4*)feats;
  if (blockIdx.x < BBLK) {
    int nB = g_nB;
    int lane = threadIdx.x & 63;
    int wid = blockIdx.x*4 + (threadIdx.x >> 6);
    int grp = lane/20;
    int c4 = lane - grp*20;
    bool act = lane < 60;
    for (int it = wid; it < nB; it += BBLK*4) {
      int2 e = g_chunkB[it];
      int c = e.x, s0 = e.y;
      int o0 = g_offs[c], o1 = g_offs[c+1];
      int s1 = min(s0 + CHK, o1);
      float ax=0.f, ay=0.f, az=0.f, aw=0.f;
      if (act) {
        int j = s0 + grp;
        for (; j + 9 < s1; j += 12) {
          int p0=g_plist[j], p1=g_plist[j+3], p2=g_plist[j+6], p3=g_plist[j+9];
          float4 v0=f4[(size_t)p0*20+c4], v1=f4[(size_t)p1*20+c4];
          float4 v2=f4[(size_t)p2*20+c4], v3=f4[(size_t)p3*20+c4];
          ax += v0.x+v1.x+v2.x+v3.x;
          ay += v0.y+v1.y+v2.y+v3.y;
          az += v0.z+v1.z+v2.z+v3.z;
          aw += v0.w+v1.w+v2.w+v3.w;
        }
        for (; j < s1; j += 3) {
          int p = g_plist[j];
          float4 v = f4[(size_t)p*20+c4];
          ax+=v.x; ay+=v.y; az+=v.z; aw+=v.w;
        }
      }
      float bx=__shfl(ax,c4+20), by=__shfl(ay,c4+20), bz=__shfl(az,c4+20), bw=__shfl(aw,c4+20);
      float cx=__shfl(ax,c4+40), cy=__shfl(ay,c4+40), cz=__shfl(az,c4+40), cw=__shfl(aw,c4+40);
      if (lane < 20) {
        ax += bx + cx; ay += by + cy; az += bz + cz; aw += bw + cw;
        int b = c / NCELL;
        int xy = c - b*NCELL;
        float* dst = out + (size_t)(b*C_ + c4*4)*NCELL + xy;
        if (o1 - o0 <= CHK) {                      // sole chunk -> exclusive
          dst[0]       = ax;
          dst[NCELL]   = ay;
          dst[2*NCELL] = az;
          dst[3*NCELL] = aw;
        } else {
          atomicAdd(dst,         ax);
          atomicAdd(dst+NCELL,   ay);
          atomicAdd(dst+2*NCELL, az);
          atomicAdd(dst+3*NCELL, aw);
        }
      }
    }
  } else {
    int nS = g_nS;
    int tot = nS*20;
    for (int i = (blockIdx.x - BBLK)*256 + threadIdx.x; i < tot; i += SBLK*256) {
      int ci = i/20;
      int c4 = i - ci*20;
      int2 e = g_cellS[ci];
      int c = e.x, o0 = e.y;
      int o1 = g_offs[c+1];
      float ax=0.f, ay=0.f, az=0.f, aw=0.f;
      int j = o0;
      for (; j + 8 <= o1; j += 8) {
        int p0=g_plist[j],   p1=g_plist[j+1], p2=g_plist[j+2], p3=g_plist[j+3];
        int p4=g_plist[j+4], p5=g_plist[j+5], p6=g_plist[j+6], p7=g_plist[j+7];
        float4 v0=f4[(size_t)p0*20+c4], v1=f4[(size_t)p1*20+c4];
        float4 v2=f4[(size_t)p2*20+c4], v3=f4[(size_t)p3*20+c4];
        float4 v4=f4[(size_t)p4*20+c4], v5=f4[(size_t)p5*20+c4];
        float4 v6=f4[(size_t)p6*20+c4], v7=f4[(size_t)p7*20+c4];
        ax += (v0.x+v1.x)+(v2.x+v3.x)+(v4.x+v5.x)+(v6.x+v7.x);
        ay += (v0.y+v1.y)+(v2.y+v3.y)+(v4.y+v5.y)+(v6.y+v7.y);
        az += (v0.z+v1.z)+(v2.z+v3.z)+(v4.z+v5.z)+(v6.z+v7.z);
        aw += (v0.w+v1.w)+(v2.w+v3.w)+(v4.w+v5.w)+(v6.w+v7.w);
      }
      for (; j < o1; ++j) {
        int p = g_plist[j];
        float4 v = f4[(size_t)p*20+c4];
        ax+=v.x; ay+=v.y; az+=v.z; aw+=v.w;
      }
      int b = c / NCELL;
      int xy = c - b*NCELL;
      float* dst = out + (size_t)(b*C_ + c4*4)*NCELL + xy;
      dst[0]       = ax;
      dst[NCELL]   = ay;
      dst[2*NCELL] = az;
      dst[3*NCELL] = aw;
    }
  }
}

extern "C" void kernel_launch(void* const* d_in, const int* in_sizes, int n_in,
                              void* d_out, int out_size, void* d_ws, size_t ws_size,
                              hipStream_t stream) {
  const float* feats  = (const float*)d_in[0];
  const float* itrans = (const float*)d_in[1];
  const float* iscale = (const float*)d_in[2];
  const float* l2i    = (const float*)d_in[3];
  float* out = (float*)d_out;

  k_init<<<OUT4/256, 256, 0, stream>>>(l2i, out);         // 20,250 blocks
  k_geom<<<NPTS/256, 256, 0, stream>>>(itrans, iscale);   // 7,788 blocks
  k_scanA<<<254, 1024, 0, stream>>>();
  k_scanB<<<1, 256, 0, stream>>>();
  k_scanC<<<254, 1024, 0, stream>>>();
  k_fill<<<NPTS/256, 256, 0, stream>>>();                 // 7,788 blocks
  k_gather<<<TOTBLK, 256, 0, stream>>>(feats, out);       // 2,048 blocks
}